// Round 8
// baseline (126.967 us; speedup 1.0000x reference)
//
#include <hip/hip_runtime.h>
#include <hip/hip_bf16.h>

typedef __attribute__((ext_vector_type(8))) short bfrag;
typedef __attribute__((ext_vector_type(4))) float facc;
typedef __attribute__((ext_vector_type(4))) int ivec4;
typedef __attribute__((ext_vector_type(2))) int ivec2;
typedef __attribute__((ext_vector_type(4))) short svec4;

#define DIN 195
#define H1 128
#define H2 64
#define CPB 4
#define ROWS 128
#define TPB 512
#define X1STR 136
#define VSTR 72

#define W1T_ELEMS (8*7*64*8)   // [mtile][k0][lane][8]
#define W2T_ELEMS (4*4*64*8)   // [ntile][k0][lane][8]

__device__ __forceinline__ short f2bf(float v) {
    __hip_bfloat16 h = __float2bfloat16(v);
    return __builtin_bit_cast(short, h);
}
__device__ __forceinline__ float celu1(float v) {
    return v > 0.f ? v : (__expf(v) - 1.f);
}

// W1t: A-fragment order. Column permutation: kp<192 -> orig 3+kp (ei|ej|ek),
// kp 192..194 -> orig 0..2 (dij,dik,djkn), kp==195 -> b1 (bias column), else 0.
__global__ void prep_weights(const float* __restrict__ W1, const float* __restrict__ W2,
                             const float* __restrict__ b1,
                             __hip_bfloat16* __restrict__ W1t, __hip_bfloat16* __restrict__ W2t) {
    int i = blockIdx.x * 256 + threadIdx.x;
    if (i < W1T_ELEMS) {
        int e = i & 7, l = (i >> 3) & 63;
        int k0 = (i >> 9) % 7, mt = (i >> 9) / 7;
        int h = mt * 16 + (l & 15);
        int kp = k0 * 32 + ((l >> 4) & 3) * 8 + e;
        float v = 0.f;
        if (kp < 192)       v = W1[h * DIN + 3 + kp];
        else if (kp < 195)  v = W1[h * DIN + (kp - 192)];
        else if (kp == 195) v = b1[h];
        W1t[i] = __float2bfloat16(v);
    } else {
        int j = i - W1T_ELEMS;
        if (j < W2T_ELEMS) {
            int e = j & 7, l = (j >> 3) & 63;
            int k0 = (j >> 9) & 3, nt = j >> 11;
            int h = nt * 16 + (l & 15);
            int k = k0 * 32 + ((l >> 4) & 3) * 8 + e;
            W2t[j] = __float2bfloat16(W2[h * H1 + k]);
        }
    }
}

template<bool PREP>
__global__ __launch_bounds__(TPB, 6) void angnet(
    const float* __restrict__ atoms_xyz,
    const float* __restrict__ embed,
    const float* __restrict__ dist_ij,
    const float* __restrict__ b1,
    const float* __restrict__ b2,
    const int* __restrict__ atype,
    const int* __restrict__ aidx,
    const int* __restrict__ ajdx,
    const __hip_bfloat16* __restrict__ W1t,
    const __hip_bfloat16* __restrict__ W2t,
    const float* __restrict__ W1f,
    const float* __restrict__ W2f,
    float* __restrict__ out)
{
    __shared__ __align__(16) __hip_bfloat16 x1s[ROWS][X1STR];     // 34816 B (staging aliased at start)
    __shared__ __align__(16) __hip_bfloat16 vst[CPB][7][VSTR];    //  4032 B
    __shared__ __align__(16) __hip_bfloat16 tvp[512];             //  1024 B: tailv[128][4] then partials[8][64]
    __shared__ __hip_bfloat16 fcs[ROWS];                          //   256 B

    // staging aliased into x1s (dead once epilogue-1 writes x1s)
    float* stg  = (float*)&x1s[0][0];      // [0..71] xyzs(c,n,ax)=stg[c*18+n*3+ax]; [72..95] dstage(c,n)=stg[72+c*6+n]
    int*   tidxp = (int*)(stg + 96);       // [0..31] tidx(c,r) at c*8+r (pow2 stride)

    const int tid = threadIdx.x;
    const int C0 = blockIdx.x * CPB;
    const int w = tid >> 6, l = tid & 63, lr = l & 15, lq = l >> 4;

    // ---- Phase 1: zero tailv, stage indices / xyz / dist ----
    if (tid < 64) {
        ivec4 zz = {0, 0, 0, 0};
        ((ivec4*)tvp)[tid] = zz;
    } else if (tid >= 64 && tid < 96) {
        int q = tid - 64, c = q >> 3, r = q & 7;   // pow2: 8 slots per c, r==7 idle
        if (r < 7)
            tidxp[c * 8 + r] = (r == 6) ? atype[aidx[C0 + c]] : atype[ajdx[(C0 + c) * 6 + r]];
    } else if (tid >= 96 && tid < 168) {
        int q = tid - 96, c = q / 18, rr = q % 18, n = rr / 3, ax = rr % 3;
        stg[c * 18 + n * 3 + ax] = atoms_xyz[(long)ajdx[(C0 + c) * 6 + n] * 3 + ax];
    } else if (tid >= 168 && tid < 192) {
        int q = tid - 168, c = q / 6, n = q % 6;
        stg[72 + c * 6 + n] = dist_ij[(C0 + c) * 6 + n];
    }
    __syncthreads();

    // ---- Phase 2: build vst (7 distinct 64-vectors per center) + per-row scalars ----
    if (tid < 256) {                                  // pow2 map: c=tid>>6, v=(tid>>3)&7 (v==7 idle), ch=tid&7
        int c = tid >> 6, v = (tid >> 3) & 7, ch = tid & 7;
        if (v < 7) {
            int ti = tidxp[c * 8 + v];
            float sc = (v < 6) ? (1.0f / stg[72 + c * 6 + v]) : 1.0f;
            const float* ep = &embed[ti * 64 + ch * 8];
            float4 e0 = *(const float4*)ep;
            float4 e1 = *(const float4*)(ep + 4);
            bfrag t;
            t[0] = f2bf(e0.x * sc); t[1] = f2bf(e0.y * sc);
            t[2] = f2bf(e0.z * sc); t[3] = f2bf(e0.w * sc);
            t[4] = f2bf(e1.x * sc); t[5] = f2bf(e1.y * sc);
            t[6] = f2bf(e1.z * sc); t[7] = f2bf(e1.w * sc);
            *(bfrag*)&vst[c][v][ch * 8] = t;
        }
    } else if (tid >= 256 && tid < 384) {             // one row each: r = tid-256
        int r = tid - 256, c = r >> 5, t = r & 31;
        if (t < 30) {
            int j = t / 5, k2 = t - j * 5, k = k2 + (k2 >= j ? 1 : 0);
            float dij = stg[72 + c * 6 + j], dik = stg[72 + c * 6 + k];
            float dx = stg[c * 18 + j * 3 + 0] - stg[c * 18 + k * 3 + 0];
            float dy = stg[c * 18 + j * 3 + 1] - stg[c * 18 + k * 3 + 1];
            float dz = stg[c * 18 + j * 3 + 2] - stg[c * 18 + k * 3 + 2];
            float djk = sqrtf(dx * dx + dy * dy + dz * dz);
            float mx = fmaxf(dij, dik), mn = fminf(dij, dik);
            float djkn = (djk - mx + mn) / (2.0f * mn);
            svec4 pk;
            pk[0] = f2bf(dij); pk[1] = f2bf(dik); pk[2] = f2bf(djkn); pk[3] = f2bf(1.0f);
            *(svec4*)&tvp[r * 4] = pk;
            const float PIF = 3.14159265358979323846f;
            float ca = __cosf(PIF * (dij * (1.0f / 3.5f)));
            float cb = __cosf(PIF * (dik * (1.0f / 3.5f)));
            fcs[r] = __float2bfloat16((0.5f * ca + 0.5f) * (0.5f * cb + 0.5f));
        } else {
            fcs[r] = __float2bfloat16(0.f);
        }
    }
    __syncthreads();

    // ---- GEMM1: D1[h][r], wave w owns h in [16w,16w+16), all 128 r ----
    // per-thread loop-invariant B addressing
    int jA = lr / 5, k2A = lr % 5; int kA = k2A + (k2A >= jA ? 1 : 0);
    int tB = 16 + lr, jB = 0, kB = 0;
    if (tB < 30) { jB = tB / 5; int k2B = tB % 5; kB = k2B + (k2B >= jB ? 1 : 0); }
    const int joA = jA * VSTR, joB = jB * VSTR, koA = kA * VSTR, koB = kB * VSTR;
    const __hip_bfloat16* vb[4];
    #pragma unroll
    for (int c = 0; c < 4; ++c) vb[c] = &vst[c][0][lq * 8];

    facc a1[8];
    #pragma unroll
    for (int n = 0; n < 8; ++n) a1[n] = (facc){0.f, 0.f, 0.f, 0.f};

    #pragma unroll
    for (int k0 = 0; k0 < 7; ++k0) {
        bfrag Af;
        if (PREP) {
            Af = *(const bfrag*)&W1t[(w * 7 + k0) * 512 + l * 8];
        } else {
            #pragma unroll
            for (int e = 0; e < 8; ++e) {
                int kp = k0 * 32 + lq * 8 + e;
                int h = w * 16 + lr;
                float v = 0.f;
                if (kp < 192)       v = W1f[h * DIN + 3 + kp];
                else if (kp < 195)  v = W1f[h * DIN + kp - 192];
                else if (kp == 195) v = b1[h];
                Af[e] = f2bf(v);
            }
        }
        #pragma unroll
        for (int n = 0; n < 8; ++n) {
            bfrag Bf;
            if (k0 < 6) {
                const __hip_bfloat16* bp;
                if (k0 < 2)      bp = vb[n >> 1] + 6 * VSTR + (k0 & 1) * 32;
                else if (k0 < 4) bp = vb[n >> 1] + ((n & 1) ? joB : joA) + (k0 & 1) * 32;
                else             bp = vb[n >> 1] + ((n & 1) ? koB : koA) + (k0 & 1) * 32;
                Bf = *(const bfrag*)bp;
            } else {
                // tail tile: only lq==0 lanes carry data (kp 192..199), rest zero
                svec4 tv = *(const svec4*)&tvp[(n * 16 + lr) * 4];
                ivec2 ti = __builtin_bit_cast(ivec2, tv);
                int lo = (lq == 0) ? ti[0] : 0;
                int hi = (lq == 0) ? ti[1] : 0;
                ivec4 bi = {lo, hi, 0, 0};
                Bf = __builtin_bit_cast(bfrag, bi);
            }
            a1[n] = __builtin_amdgcn_mfma_f32_16x16x32_bf16(Af, Bf, a1[n], 0, 0, 0);
        }
    }

    // ---- Epilogue 1: celu -> x1s (bias folded into GEMM1) ----
    #pragma unroll
    for (int n = 0; n < 8; ++n) {
        svec4 pk;
        #pragma unroll
        for (int g = 0; g < 4; ++g) pk[g] = f2bf(celu1(a1[n][g]));
        *(svec4*)&x1s[n * 16 + lr][w * 16 + lq * 4] = pk;
    }
    __syncthreads();

    // ---- GEMM2: D2[r][o]; wave w owns rows [16w,16w+16), all 64 o ----
    facc a2[4];
    #pragma unroll
    for (int n = 0; n < 4; ++n) a2[n] = (facc){0.f, 0.f, 0.f, 0.f};

    #pragma unroll
    for (int k0 = 0; k0 < 4; ++k0) {
        bfrag Af2 = *(const bfrag*)&x1s[w * 16 + lr][k0 * 32 + lq * 8];
        #pragma unroll
        for (int n = 0; n < 4; ++n) {
            bfrag Bf2;
            if (PREP) {
                Bf2 = *(const bfrag*)&W2t[(n * 4 + k0) * 512 + l * 8];
            } else {
                #pragma unroll
                for (int e = 0; e < 8; ++e)
                    Bf2[e] = f2bf(W2f[(n * 16 + lr) * H1 + k0 * 32 + lq * 8 + e]);
            }
            a2[n] = __builtin_amdgcn_mfma_f32_16x16x32_bf16(Af2, Bf2, a2[n], 0, 0, 0);
        }
    }

    // ---- Epilogue 2: celu + fc, g-sum + 2 shfls, bf16 partials ----
    {
        float fr[4];
        #pragma unroll
        for (int g = 0; g < 4; ++g) fr[g] = __bfloat162float(fcs[w * 16 + lq * 4 + g]);
        float t[4];
        #pragma unroll
        for (int n = 0; n < 4; ++n) {
            float b2v = b2[n * 16 + lr];
            float s = 0.f;
            #pragma unroll
            for (int g = 0; g < 4; ++g)
                s += celu1(a2[n][g] + b2v) * fr[g];
            s += __shfl_xor(s, 16);
            s += __shfl_xor(s, 32);
            t[n] = s;
        }
        if (lq == 0) {
            #pragma unroll
            for (int n = 0; n < 4; ++n)
                tvp[w * 64 + n * 16 + lr] = __float2bfloat16(t[n]);
        }
    }
    __syncthreads();

    // ---- Final: combine the two half-center partials, coalesced store ----
    if (tid < 256) {
        int c = tid >> 6, o = tid & 63;
        out[(long)(C0 + c) * 64 + o] =
            __bfloat162float(tvp[(2 * c) * 64 + o]) + __bfloat162float(tvp[(2 * c + 1) * 64 + o]);
    }
}

extern "C" void kernel_launch(void* const* d_in, const int* in_sizes, int n_in,
                              void* d_out, int out_size, void* d_ws, size_t ws_size,
                              hipStream_t stream) {
    const float* atoms_xyz = (const float*)d_in[0];
    const float* embed     = (const float*)d_in[1];
    const float* dist_ij   = (const float*)d_in[2];
    const float* W1        = (const float*)d_in[3];
    const float* b1        = (const float*)d_in[4];
    const float* W2        = (const float*)d_in[5];
    const float* b2        = (const float*)d_in[6];
    const int*   atype     = (const int*)d_in[7];
    const int*   aidx      = (const int*)d_in[8];
    const int*   ajdx      = (const int*)d_in[9];
    float* out = (float*)d_out;

    const int n_center = in_sizes[8];            // 40000
    const int n_blocks = n_center / CPB;         // 10000

    size_t need = (size_t)(W1T_ELEMS + W2T_ELEMS) * sizeof(__hip_bfloat16);
    if (ws_size >= need) {
        __hip_bfloat16* W1t = (__hip_bfloat16*)d_ws;
        __hip_bfloat16* W2t = W1t + W1T_ELEMS;
        int prep_total = W1T_ELEMS + W2T_ELEMS;
        prep_weights<<<(prep_total + 255) / 256, 256, 0, stream>>>(W1, W2, b1, W1t, W2t);
        angnet<true><<<n_blocks, TPB, 0, stream>>>(atoms_xyz, embed, dist_ij, b1, b2,
                                                   atype, aidx, ajdx, W1t, W2t, W1, W2, out);
    } else {
        angnet<false><<<n_blocks, TPB, 0, stream>>>(atoms_xyz, embed, dist_ij, b1, b2,
                                                    atype, aidx, ajdx, nullptr, nullptr, W1, W2, out);
    }
}

// Round 9
// 116.733 us; speedup vs baseline: 1.0877x; 1.0877x over previous
//
#include <hip/hip_runtime.h>
#include <hip/hip_bf16.h>

typedef __attribute__((ext_vector_type(8))) short bfrag;
typedef __attribute__((ext_vector_type(4))) float facc;
typedef __attribute__((ext_vector_type(4))) int ivec4;
typedef __attribute__((ext_vector_type(2))) int ivec2;
typedef __attribute__((ext_vector_type(4))) short svec4;

#define DIN 195
#define H1 128
#define H2 64
#define CPB 4
#define ROWS 128
#define TPB 512
#define X1STR 136
#define VSTR 72

#define W1T_ELEMS (8*7*64*8)   // [mtile][k0][lane][8]
#define W2T_ELEMS (4*4*64*8)   // [ntile][k0][lane][8]

__device__ __forceinline__ short f2bf(float v) {
    __hip_bfloat16 h = __float2bfloat16(v);
    return __builtin_bit_cast(short, h);
}
__device__ __forceinline__ float celu1(float v) {
    return v > 0.f ? v : (__expf(v) - 1.f);
}

// W1t: A-fragment order. Column permutation: kp<192 -> orig 3+kp (ei|ej|ek),
// kp 192..194 -> orig 0..2 (dij,dik,djkn), kp==195 -> b1 (bias column), else 0.
__global__ void prep_weights(const float* __restrict__ W1, const float* __restrict__ W2,
                             const float* __restrict__ b1,
                             __hip_bfloat16* __restrict__ W1t, __hip_bfloat16* __restrict__ W2t) {
    int i = blockIdx.x * 256 + threadIdx.x;
    if (i < W1T_ELEMS) {
        int e = i & 7, l = (i >> 3) & 63;
        int k0 = (i >> 9) % 7, mt = (i >> 9) / 7;
        int h = mt * 16 + (l & 15);
        int kp = k0 * 32 + ((l >> 4) & 3) * 8 + e;
        float v = 0.f;
        if (kp < 192)       v = W1[h * DIN + 3 + kp];
        else if (kp < 195)  v = W1[h * DIN + (kp - 192)];
        else if (kp == 195) v = b1[h];
        W1t[i] = __float2bfloat16(v);
    } else {
        int j = i - W1T_ELEMS;
        if (j < W2T_ELEMS) {
            int e = j & 7, l = (j >> 3) & 63;
            int k0 = (j >> 9) & 3, nt = j >> 11;
            int h = nt * 16 + (l & 15);
            int k = k0 * 32 + ((l >> 4) & 3) * 8 + e;
            W2t[j] = __float2bfloat16(W2[h * H1 + k]);
        }
    }
}

template<bool PREP>
__global__ __launch_bounds__(TPB, 8) void angnet(
    const float* __restrict__ atoms_xyz,
    const float* __restrict__ embed,
    const float* __restrict__ dist_ij,
    const float* __restrict__ b1,
    const float* __restrict__ b2,
    const int* __restrict__ atype,
    const int* __restrict__ aidx,
    const int* __restrict__ ajdx,
    const __hip_bfloat16* __restrict__ W1t,
    const __hip_bfloat16* __restrict__ W2t,
    const float* __restrict__ W1f,
    const float* __restrict__ W2f,
    float* __restrict__ out)
{
    __shared__ __align__(16) __hip_bfloat16 x1s[ROWS][X1STR];     // 34816 B; bytes 1024..2047 = zero-page pre-GEMM1
    __shared__ __align__(16) __hip_bfloat16 vst[CPB][7][VSTR];    //  4032 B
    __shared__ __align__(16) __hip_bfloat16 tvp[512];             //  1024 B: tailv[128][4] then partials[8][64]
    __shared__ __hip_bfloat16 fcs[ROWS];                          //   256 B

    const int tid = threadIdx.x;
    const int C0 = blockIdx.x * CPB;
    const int w = tid >> 6, l = tid & 63, lr = l & 15, lq = l >> 4;

    // ---- Phase A: single setup phase, all loads direct from global (L1 broadcasts) ----
    if (tid < 256) {                                  // vst build: c=tid>>6, v=(tid>>3)&7 (v==7 idle), ch=tid&7
        int c = tid >> 6, v = (tid >> 3) & 7, ch = tid & 7;
        if (v < 7) {
            int ti = (v == 6) ? atype[aidx[C0 + c]] : atype[ajdx[(C0 + c) * 6 + v]];
            float sc = 1.0f;
            if (v < 6) sc = 1.0f / dist_ij[(C0 + c) * 6 + v];
            const float* ep = &embed[ti * 64 + ch * 8];
            float4 e0 = *(const float4*)ep;
            float4 e1 = *(const float4*)(ep + 4);
            bfrag t;
            t[0] = f2bf(e0.x * sc); t[1] = f2bf(e0.y * sc);
            t[2] = f2bf(e0.z * sc); t[3] = f2bf(e0.w * sc);
            t[4] = f2bf(e1.x * sc); t[5] = f2bf(e1.y * sc);
            t[6] = f2bf(e1.z * sc); t[7] = f2bf(e1.w * sc);
            *(bfrag*)&vst[c][v][ch * 8] = t;
        }
    } else if (tid < 384) {                           // tailv rows + fcs, direct loads
        int r = tid - 256, c = r >> 5, t = r & 31;
        if (t < 30) {
            int j = t / 5, k2 = t - j * 5, k = k2 + (k2 >= j ? 1 : 0);
            long bj = ajdx[(C0 + c) * 6 + j];
            long bk = ajdx[(C0 + c) * 6 + k];
            float dij = dist_ij[(C0 + c) * 6 + j];
            float dik = dist_ij[(C0 + c) * 6 + k];
            float dx = atoms_xyz[bj * 3 + 0] - atoms_xyz[bk * 3 + 0];
            float dy = atoms_xyz[bj * 3 + 1] - atoms_xyz[bk * 3 + 1];
            float dz = atoms_xyz[bj * 3 + 2] - atoms_xyz[bk * 3 + 2];
            float djk = sqrtf(dx * dx + dy * dy + dz * dz);
            float mx = fmaxf(dij, dik), mn = fminf(dij, dik);
            float djkn = (djk - mx + mn) / (2.0f * mn);
            svec4 pk;
            pk[0] = f2bf(dij); pk[1] = f2bf(dik); pk[2] = f2bf(djkn); pk[3] = f2bf(1.0f);
            *(svec4*)&tvp[r * 4] = pk;
            const float PIF = 3.14159265358979323846f;
            float ca = __cosf(PIF * (dij * (1.0f / 3.5f)));
            float cb = __cosf(PIF * (dik * (1.0f / 3.5f)));
            fcs[r] = __float2bfloat16((0.5f * ca + 0.5f) * (0.5f * cb + 0.5f));
        } else {
            svec4 zz4 = {0, 0, 0, 0};
            *(svec4*)&tvp[r * 4] = zz4;               // pad rows of tailv -> zero (also zeroes bias col)
            fcs[r] = __float2bfloat16(0.f);
        }
    } else if (tid < 448) {                           // zero-page: x1s bytes 1024..2047
        int q = tid - 384;
        ivec4 zz = {0, 0, 0, 0};
        *(ivec4*)((char*)&x1s[0][0] + 1024 + q * 16) = zz;
    }
    __syncthreads();

    // ---- GEMM1: D1[h][r], wave w owns h in [16w,16w+16), all 128 r ----
    int jA = lr / 5, k2A = lr % 5; int kA = k2A + (k2A >= jA ? 1 : 0);
    int tB = 16 + lr, jB = 0, kB = 0;
    if (tB < 30) { jB = tB / 5; int k2B = tB % 5; kB = k2B + (k2B >= jB ? 1 : 0); }
    const int joA = jA * VSTR, joB = jB * VSTR, koA = kA * VSTR, koB = kB * VSTR;
    const __hip_bfloat16* vb[4];
    #pragma unroll
    for (int c = 0; c < 4; ++c) vb[c] = &vst[c][0][lq * 8];

    // tail base: lq==0 lanes read real tailv, others read the zero-page (single select, then imm offsets)
    const __hip_bfloat16* zbase = (const __hip_bfloat16*)((char*)&x1s[0][0] + 1024);
    const __hip_bfloat16* tbase = (lq == 0) ? &tvp[lr * 4] : &zbase[lr * 4];

    facc a1[8];
    #pragma unroll
    for (int n = 0; n < 8; ++n) a1[n] = (facc){0.f, 0.f, 0.f, 0.f};

    #pragma unroll
    for (int k0 = 0; k0 < 7; ++k0) {
        bfrag Af;
        if (PREP) {
            Af = *(const bfrag*)&W1t[(w * 7 + k0) * 512 + l * 8];
        } else {
            #pragma unroll
            for (int e = 0; e < 8; ++e) {
                int kp = k0 * 32 + lq * 8 + e;
                int h = w * 16 + lr;
                float v = 0.f;
                if (kp < 192)       v = W1f[h * DIN + 3 + kp];
                else if (kp < 195)  v = W1f[h * DIN + kp - 192];
                else if (kp == 195) v = b1[h];
                Af[e] = f2bf(v);
            }
        }
        #pragma unroll
        for (int n = 0; n < 8; ++n) {
            bfrag Bf;
            if (k0 < 6) {
                const __hip_bfloat16* bp;
                if (k0 < 2)      bp = vb[n >> 1] + 6 * VSTR + (k0 & 1) * 32;
                else if (k0 < 4) bp = vb[n >> 1] + ((n & 1) ? joB : joA) + (k0 & 1) * 32;
                else             bp = vb[n >> 1] + ((n & 1) ? koB : koA) + (k0 & 1) * 32;
                Bf = *(const bfrag*)bp;
            } else {
                ivec2 tv = *(const ivec2*)(tbase + n * 64);   // n*128 bytes imm offset
                ivec4 bi = {tv[0], tv[1], 0, 0};
                Bf = __builtin_bit_cast(bfrag, bi);
            }
            a1[n] = __builtin_amdgcn_mfma_f32_16x16x32_bf16(Af, Bf, a1[n], 0, 0, 0);
        }
    }

    // ---- Epilogue 1: celu -> x1s (bias folded into GEMM1) ----
    #pragma unroll
    for (int n = 0; n < 8; ++n) {
        svec4 pk;
        #pragma unroll
        for (int g = 0; g < 4; ++g) pk[g] = f2bf(celu1(a1[n][g]));
        *(svec4*)&x1s[n * 16 + lr][w * 16 + lq * 4] = pk;
    }
    __syncthreads();

    // ---- GEMM2: D2[r][o]; wave w owns rows [16w,16w+16), all 64 o ----
    facc a2[4];
    #pragma unroll
    for (int n = 0; n < 4; ++n) a2[n] = (facc){0.f, 0.f, 0.f, 0.f};

    #pragma unroll
    for (int k0 = 0; k0 < 4; ++k0) {
        bfrag Af2 = *(const bfrag*)&x1s[w * 16 + lr][k0 * 32 + lq * 8];
        #pragma unroll
        for (int n = 0; n < 4; ++n) {
            bfrag Bf2;
            if (PREP) {
                Bf2 = *(const bfrag*)&W2t[(n * 4 + k0) * 512 + l * 8];
            } else {
                #pragma unroll
                for (int e = 0; e < 8; ++e)
                    Bf2[e] = f2bf(W2f[(n * 16 + lr) * H1 + k0 * 32 + lq * 8 + e]);
            }
            a2[n] = __builtin_amdgcn_mfma_f32_16x16x32_bf16(Af2, Bf2, a2[n], 0, 0, 0);
        }
    }

    // ---- Epilogue 2: celu + fc, g-sum + 2 shfls, bf16 partials ----
    {
        float fr[4];
        #pragma unroll
        for (int g = 0; g < 4; ++g) fr[g] = __bfloat162float(fcs[w * 16 + lq * 4 + g]);
        float t[4];
        #pragma unroll
        for (int n = 0; n < 4; ++n) {
            float b2v = b2[n * 16 + lr];
            float s = 0.f;
            #pragma unroll
            for (int g = 0; g < 4; ++g)
                s += celu1(a2[n][g] + b2v) * fr[g];
            s += __shfl_xor(s, 16);
            s += __shfl_xor(s, 32);
            t[n] = s;
        }
        if (lq == 0) {
            #pragma unroll
            for (int n = 0; n < 4; ++n)
                tvp[w * 64 + n * 16 + lr] = __float2bfloat16(t[n]);
        }
    }
    __syncthreads();

    // ---- Final: combine the two half-center partials, coalesced store ----
    if (tid < 256) {
        int c = tid >> 6, o = tid & 63;
        out[(long)(C0 + c) * 64 + o] =
            __bfloat162float(tvp[(2 * c) * 64 + o]) + __bfloat162float(tvp[(2 * c + 1) * 64 + o]);
    }
}

extern "C" void kernel_launch(void* const* d_in, const int* in_sizes, int n_in,
                              void* d_out, int out_size, void* d_ws, size_t ws_size,
                              hipStream_t stream) {
    const float* atoms_xyz = (const float*)d_in[0];
    const float* embed     = (const float*)d_in[1];
    const float* dist_ij   = (const float*)d_in[2];
    const float* W1        = (const float*)d_in[3];
    const float* b1        = (const float*)d_in[4];
    const float* W2        = (const float*)d_in[5];
    const float* b2        = (const float*)d_in[6];
    const int*   atype     = (const int*)d_in[7];
    const int*   aidx      = (const int*)d_in[8];
    const int*   ajdx      = (const int*)d_in[9];
    float* out = (float*)d_out;

    const int n_center = in_sizes[8];            // 40000
    const int n_blocks = n_center / CPB;         // 10000

    size_t need = (size_t)(W1T_ELEMS + W2T_ELEMS) * sizeof(__hip_bfloat16);
    if (ws_size >= need) {
        __hip_bfloat16* W1t = (__hip_bfloat16*)d_ws;
        __hip_bfloat16* W2t = W1t + W1T_ELEMS;
        int prep_total = W1T_ELEMS + W2T_ELEMS;
        prep_weights<<<(prep_total + 255) / 256, 256, 0, stream>>>(W1, W2, b1, W1t, W2t);
        angnet<true><<<n_blocks, TPB, 0, stream>>>(atoms_xyz, embed, dist_ij, b1, b2,
                                                   atype, aidx, ajdx, W1t, W2t, W1, W2, out);
    } else {
        angnet<false><<<n_blocks, TPB, 0, stream>>>(atoms_xyz, embed, dist_ij, b1, b2,
                                                    atype, aidx, ajdx, nullptr, nullptr, W1, W2, out);
    }
}